// Round 7
// baseline (32.499 us; speedup 1.0000x reference)
//
#include <hip/hip_runtime.h>

typedef float floatx4 __attribute__((ext_vector_type(4)));

// Problem constants
constexpr int H    = 768;
constexpr int W4   = 1280 / 4;        // float4 per row = 320
constexpr int PAD  = 4;               // shift == one float4 (aligned!)
constexpr int NVEC = 16 * 768 * W4;   // 3,932,160 float4 elements
constexpr int UNROLL = 4;
constexpr int BLOCK  = 256;
constexpr int PER_BLOCK = BLOCK * UNROLL;      // 1024
constexpr int GRID = NVEC / PER_BLOCK;         // 3840 (exact)
constexpr int NXCD  = 8;
constexpr int CHUNK = GRID / NXCD;             // 480 (bijective: GRID % 8 == 0)

__global__ __launch_bounds__(256)
void bilateral_kernel(const floatx4* __restrict__ img,
                      const floatx4* __restrict__ disp,
                      floatx4* __restrict__ out)
{
    // XCD-aware swizzle (R3 WIN: FETCH 93->62 MB): each XCD owns a contiguous
    // 480-block chunk, so the +1281-vec shifted img window is same-XCD L2.
    const int bid = blockIdx.x;
    const int swz = (bid % NXCD) * CHUNK + bid / NXCD;
    const int base = swz * PER_BLOCK + threadIdx.x;

    const float DIST = 0.16901332f;   // exp(-16/9), spatial gaussian at (4,4)
    const float EPS  = 1e-12f;

    int     idx[UNROLL];
    floatx4 a[UNROLL], s[UNROLL], d[UNROLL];
    bool    sOK[UNROLL], dOK[UNROLL];

    // ---- load section: compiler loads, branch-free (clamp + cndmask) ----
#pragma unroll
    for (int k = 0; k < UNROLL; ++k) {
        idx[k] = base + k * BLOCK;
        const int c4 = idx[k] % W4;
        const int r  = (idx[k] / W4) % H;
        sOK[k] = (r + PAD < H) & (c4 + 1 < W4);
        dOK[k] = (r >= PAD) & (c4 >= 1);
        const int sI = sOK[k] ? idx[k] + PAD * W4 + 1 : idx[k];
        const int dI = dOK[k] ? idx[k] - PAD * W4 - 1 : idx[k];
        a[k] = img[idx[k]];
        s[k] = img[sI];
        d[k] = disp[dI];
    }

    __builtin_amdgcn_sched_barrier(0);

    // ---- compute + store section ----
#pragma unroll
    for (int k = 0; k < UNROLL; ++k) {
        const floatx4 sv = sOK[k] ? s[k] : (floatx4)0.0f;
        const floatx4 dv = dOK[k] ? d[k] : (floatx4)0.0f;

        floatx4 o;
#pragma unroll
        for (int j = 0; j < 4; ++j) {
            float diff = a[k][j] - sv[j];
            float w    = DIST * __expf(diff * diff * -0.125f); // exp(-diff²/8)
            o[j] = __builtin_fmaf(dv[j], w, EPS) * __builtin_amdgcn_rcpf(w + EPS);
        }

        // Streaming store, L2 no-allocate variant: nt + sc1. The 61 MB/replay
        // output stream otherwise evicts the L2/L3-resident inputs
        // (warm FETCH == WRITE_SIZE). Plain nt (R5 builtin) was neutral.
        floatx4* op = out + idx[k];
        asm volatile("global_store_dwordx4 %0, %1, off nt sc1"
                     :: "v"(op), "v"(o) : "memory");
    }
}

extern "C" void kernel_launch(void* const* d_in, const int* in_sizes, int n_in,
                              void* d_out, int out_size, void* d_ws, size_t ws_size,
                              hipStream_t stream) {
    const floatx4* img  = (const floatx4*)d_in[0];   // leftImage
    const floatx4* disp = (const floatx4*)d_in[1];   // estDisp
    floatx4* out = (floatx4*)d_out;

    bilateral_kernel<<<GRID, BLOCK, 0, stream>>>(img, disp, out);
}

// Round 8
// 31.229 us; speedup vs baseline: 1.0407x; 1.0407x over previous
//
#include <hip/hip_runtime.h>

typedef float floatx4 __attribute__((ext_vector_type(4)));

// Problem constants
constexpr int H    = 768;
constexpr int W4   = 1280 / 4;        // float4 per row = 320
constexpr int PAD  = 4;               // shift == one float4 (aligned!)
constexpr int ROWS = 16 * 768;        // B*C*H = 12288 rows (one block each)
constexpr int NXCD  = 8;
constexpr int CHUNK = ROWS / NXCD;    // 1536 (bijective: ROWS % 8 == 0)

// One block per image row: 320 threads = 5 waves, c4 = threadIdx.x (no
// per-thread div/mod). Shortest possible per-wave dependency chain: 3 loads
// issued together, one wait, compute, one store.
__global__ __launch_bounds__(320)
void bilateral_kernel(const floatx4* __restrict__ img,
                      const floatx4* __restrict__ disp,
                      floatx4* __restrict__ out)
{
    // XCD-aware swizzle (R3 WIN): contiguous 1536-row chunk per XCD so the
    // +4-row shifted img window lands in the same XCD's L2.
    const int bid  = blockIdx.x;
    const int row  = (bid % NXCD) * CHUNK + bid / NXCD;   // global row in [0, 12288)
    const int r    = row % H;                              // row within image (scalar)
    const int c4   = threadIdx.x;                          // vector column, 0..319
    const int idx  = row * W4 + c4;

    const float DIST = 0.16901332f;   // exp(-16/9), spatial gaussian at (4,4)
    const float EPS  = 1e-12f;

    const bool sOK = (r + PAD < H) & (c4 + 1 < W4);
    const bool dOK = (r >= PAD) & (c4 >= 1);

    // Branch-free: clamp OOB addresses to center, zero via cndmask after.
    const floatx4 a = img[idx];
    const floatx4 s0 = img[sOK ? idx + PAD * W4 + 1 : idx];
    const floatx4 d0 = disp[dOK ? idx - PAD * W4 - 1 : idx];

    const floatx4 s = sOK ? s0 : (floatx4)0.0f;
    const floatx4 d = dOK ? d0 : (floatx4)0.0f;

    floatx4 o;
#pragma unroll
    for (int j = 0; j < 4; ++j) {
        float diff = a[j] - s[j];
        float w    = DIST * __expf(diff * diff * -0.125f);  // exp(-diff²/8)
        o[j] = __builtin_fmaf(d[j], w, EPS) * __builtin_amdgcn_rcpf(w + EPS);
    }

    out[idx] = o;
}

extern "C" void kernel_launch(void* const* d_in, const int* in_sizes, int n_in,
                              void* d_out, int out_size, void* d_ws, size_t ws_size,
                              hipStream_t stream) {
    const floatx4* img  = (const floatx4*)d_in[0];   // leftImage
    const floatx4* disp = (const floatx4*)d_in[1];   // estDisp
    floatx4* out = (floatx4*)d_out;

    bilateral_kernel<<<ROWS, 320, 0, stream>>>(img, disp, out);
}